// Round 9
// baseline (633.863 us; speedup 1.0000x reference)
//
#include <hip/hip_runtime.h>
#include <math.h>

// EAM potential: E = sum_n F(rho_n) + 0.5 * sum_e phi(bl_e)
//   rho_n = sum_{e: dst[e]=n} density(bl_e)
//   forces = segsum(dEdr, src) - segsum(dEdr, dst)
//
// R9: int LDS atomics cracked p3b (R8). Now p3a: drop histogram+scan+compact
// (12.8M LDS atomic lane-ops, 20 barriers/block) -> fixed-cap per-(block,
// partition) LDS slabs: 1 cursor atomic/record, 2 barriers/block, per-wave
// coalesced segment flush (1 global atomic per partition per block).
// Overflow -> zeroed global u32-quanta arrays, folded in at merge.

static constexpr int SHIFT_P = 12;    // log2(nodes per partition)
static constexpr int NPP     = 4096;  // nodes per partition
static constexpr int PMAX    = 32;    // max partitions (cursor arrays)
static constexpr int KR      = 16;    // accumulation slices per partition (rho)
static constexpr int KB      = 24;    // accumulation slices per partition (force)
static constexpr int CH1     = 4096;  // edges per p1a block (4096 records)
static constexpr int CH3     = 2048;  // edges per p3a block (4096 records)
static constexpr int CAP     = 256;   // slab capacity per (block,partition)

static constexpr float QSCALE = 524288.0f;   // 2^19 (rho in [0,2))
static constexpr float QSTEP  = 1.0f / QSCALE;
static constexpr float FSCALE = 1024.0f;     // 2^10 force quantum
static constexpr float FSTEP  = 1.0f / FSCALE;

__device__ __forceinline__ double block_reduce_d(double v) {
    #pragma unroll
    for (int off = 32; off > 0; off >>= 1)
        v += __shfl_down(v, off, 64);
    __shared__ double smem[16];
    const int lane = threadIdx.x & 63;
    const int wave = threadIdx.x >> 6;
    if (threadIdx.x < 16) smem[threadIdx.x] = 0.0;
    __syncthreads();
    if (lane == 0) smem[wave] = v;
    __syncthreads();
    if (wave == 0) {
        v = (lane < 16) ? smem[lane] : 0.0;
        #pragma unroll
        for (int off = 8; off > 0; off >>= 1)
            v += __shfl_down(v, off, 64);
    }
    return v;  // valid in threadIdx.x == 0
}

__device__ __forceinline__ int clamp_idx(int i, int hi) {
    return i < 0 ? 0 : (i > hi ? hi : i);
}

__device__ __forceinline__ unsigned f2bf(float f) {
    unsigned u = __float_as_uint(f);
    return (u + 0x7FFFu + ((u >> 16) & 1u)) >> 16;   // RNE bf16
}
__device__ __forceinline__ float bf2f_hi(unsigned w) { return __uint_as_float(w & 0xFFFF0000u); }
__device__ __forceinline__ float bf2f_lo(unsigned w) { return __uint_as_float(w << 16); }
// float -> signed fixed-point quanta as unsigned (exact mod-2^32 adds)
__device__ __forceinline__ unsigned fq(float f) {
    float s = f * FSCALE;
    s = fminf(fmaxf(s, -1.0e9f), 1.0e9f);
    return (unsigned)(int)rintf(s);
}

// Interleave spline coeff tables.
__global__ void eam_prep(
    const float* __restrict__ rad_a, const float* __restrict__ rad_b,
    const float* __restrict__ rad_c, const float* __restrict__ rad_d,
    const float* __restrict__ ea, const float* __restrict__ eb,
    const float* __restrict__ ec, const float* __restrict__ ed,
    float4* __restrict__ pack8, float4* __restrict__ pack4,
    int nr1, int nrho1)
{
    const int i = blockIdx.x * 256 + threadIdx.x;
    if (i < nr1) {
        pack8[2*i]   = make_float4(rad_a[2*i], rad_a[2*i+1], rad_b[2*i], rad_b[2*i+1]);
        pack8[2*i+1] = make_float4(rad_c[2*i], rad_c[2*i+1], rad_d[2*i], rad_d[2*i+1]);
    }
    if (i < nrho1)
        pack4[i] = make_float4(ea[i], eb[i], ec[i], ed[i]);
}

// ---- rho chain ----

// Slab-partition rho records (4B: local12<<20 | q20); phi partials.
// Dynamic LDS: P*CAP u32 slab.
__global__ void __launch_bounds__(512) eam_p1a(
    const float* __restrict__ r, const int* __restrict__ dst,
    const float4* __restrict__ pack8,
    unsigned* __restrict__ recR, int* __restrict__ gCurR,
    unsigned* __restrict__ ovR, double* __restrict__ p1,
    int n_edges, float inv_h, float h, int kmax, int P, int capR)
{
    extern __shared__ unsigned slabR[];   // P*CAP
    __shared__ int cur[PMAX];
    const int tid = threadIdx.x, blk = blockIdx.x;
    for (int b = tid; b < P; b += 512) cur[b] = 0;
    __syncthreads();
    const int e0 = blk * CH1, e1 = min(e0 + CH1, n_edges);
    double phi = 0.0;
    for (int e = e0 + tid; e < e1; e += 512) {
        const float x = r[3*e], y = r[3*e+1], z = r[3*e+2];
        const float bl = sqrtf(x*x + y*y + z*z);
        int idx = (int)(bl * inv_h); idx = idx > kmax ? kmax : idx;
        const float s = bl - (float)idx * h;
        const float4 q0 = pack8[2*idx];
        const float4 q1 = pack8[2*idx + 1];
        const float rho  = q0.x + s*(q0.z + s*(q1.x + s*q1.z));
        const float rphi = q0.y + s*(q0.w + s*(q1.y + s*q1.w));
        phi += 0.5 * (double)(rphi / bl);
        const int node = dst[e];
        const int pp = node >> SHIFT_P;
        int q = (int)(rho * QSCALE + 0.5f);
        q = q < 0 ? 0 : (q > 0xFFFFF ? 0xFFFFF : q);
        const int slot = atomicAdd(&cur[pp], 1);
        if (slot < CAP)
            slabR[pp * CAP + slot] = ((unsigned)(node & (NPP - 1)) << 20) | (unsigned)q;
        else
            atomicAdd(&ovR[node], (unsigned)q);   // rare global spill (u32 quanta)
    }
    __syncthreads();
    // per-wave coalesced flush: wave w owns partitions w, w+8, ...
    const int wave = tid >> 6, lane = tid & 63;
    for (int p = wave; p < P; p += 8) {
        int c = cur[p]; c = c > CAP ? CAP : c;
        int gb = 0;
        if (lane == 0 && c > 0) gb = atomicAdd(&gCurR[p], c);
        gb = __shfl(gb, 0, 64);
        for (int i = lane; i < c; i += 64) {
            const int gi = gb + i;
            if (gi < capR) recR[(size_t)p * capR + gi] = slabR[p * CAP + i];
        }
    }
    const double bs = block_reduce_d(phi);
    if (tid == 0) p1[blk] = bs;
}

// Accumulate one slice of one partition's rho records (u32 LDS atomics).
__global__ void __launch_bounds__(512) eam_p1b(
    const unsigned* __restrict__ recR, const int* __restrict__ gCurR,
    float* __restrict__ partR, int capR)
{
    __shared__ unsigned acc[NPP];  // 16 KB
    const int tid = threadIdx.x;
    const int p = blockIdx.x / KR, j = blockIdx.x % KR;
    for (int i = tid; i < NPP; i += 512) acc[i] = 0u;
    __syncthreads();
    int cnt = gCurR[p]; cnt = cnt > capR ? capR : cnt;
    const int per = (((cnt + KR - 1) / KR) + 3) & ~3;
    const int lo = j * per, hi = min(lo + per, cnt);
    const unsigned* seg = recR + (size_t)p * capR;
    int i = lo + 4 * tid;
    for (; i + 4 * 512 + 3 < hi; i += 2 * 4 * 512) {
        const uint4 a = *(const uint4*)(seg + i);
        const uint4 b = *(const uint4*)(seg + i + 4 * 512);
        atomicAdd(&acc[a.x >> 20], a.x & 0xFFFFFu);
        atomicAdd(&acc[a.y >> 20], a.y & 0xFFFFFu);
        atomicAdd(&acc[a.z >> 20], a.z & 0xFFFFFu);
        atomicAdd(&acc[a.w >> 20], a.w & 0xFFFFFu);
        atomicAdd(&acc[b.x >> 20], b.x & 0xFFFFFu);
        atomicAdd(&acc[b.y >> 20], b.y & 0xFFFFFu);
        atomicAdd(&acc[b.z >> 20], b.z & 0xFFFFFu);
        atomicAdd(&acc[b.w >> 20], b.w & 0xFFFFFu);
    }
    for (; i + 3 < hi; i += 4 * 512) {
        const uint4 a = *(const uint4*)(seg + i);
        atomicAdd(&acc[a.x >> 20], a.x & 0xFFFFFu);
        atomicAdd(&acc[a.y >> 20], a.y & 0xFFFFFu);
        atomicAdd(&acc[a.z >> 20], a.z & 0xFFFFFu);
        atomicAdd(&acc[a.w >> 20], a.w & 0xFFFFFu);
    }
    for (int t = (hi & ~3) + tid; t < hi; t += 512) {
        const unsigned w = seg[t];
        atomicAdd(&acc[w >> 20], w & 0xFFFFFu);
    }
    __syncthreads();
    float* out = partR + (size_t)blockIdx.x * NPP;
    for (int k = tid; k < NPP; k += 512) out[k] = (float)acc[k] * QSTEP;
}

// Merge rho partials (+overflow); embedding spline -> Fp, F partial sums.
__global__ void __launch_bounds__(1024) eam_p1c(
    const float* __restrict__ partR, const unsigned* __restrict__ ovR,
    const float4* __restrict__ pack4,
    float* __restrict__ Fp, double* __restrict__ p2,
    int n_nodes, float inv_h, float h, int kmax)
{
    const int n = blockIdx.x * 1024 + threadIdx.x;
    double fsum = 0.0;
    if (n < n_nodes) {
        const int p = n >> SHIFT_P, l = n & (NPP - 1);
        float rho = (float)(int)ovR[n] * QSTEP;
        #pragma unroll
        for (int j = 0; j < KR; ++j)
            rho += partR[(size_t)(p * KR + j) * NPP + l];
        int idx = clamp_idx((int)(rho * inv_h), kmax);
        const float s = rho - (float)idx * h;
        const float4 q = pack4[idx];
        fsum = (double)(q.x + s*(q.y + s*(q.z + s*q.w)));
        Fp[n] = q.y + s*(2.0f*q.z + 3.0f*q.w*s);
    }
    const double bs = block_reduce_d(fsum);
    if (threadIdx.x == 0) p2[blockIdx.x] = bs;
}

// ---- force chain ----

// Slab-partition force records (8B: local12<<16|bf16fx, bf16fy<<16|bf16fz).
// Dynamic LDS: P*CAP int2 slab.
__global__ void __launch_bounds__(512) eam_p3a(
    const float* __restrict__ r, const int* __restrict__ src, const int* __restrict__ dst,
    const float4* __restrict__ pack8, const float* __restrict__ Fp,
    int2* __restrict__ recF, int* __restrict__ gCurF,
    unsigned* __restrict__ ovF,
    int n_edges, float inv_h, float h, int kmax, int P, int capF)
{
    extern __shared__ int2 slabF[];   // P*CAP
    __shared__ int cur[PMAX];
    const int tid = threadIdx.x, blk = blockIdx.x;
    for (int b = tid; b < P; b += 512) cur[b] = 0;
    __syncthreads();
    const int e0 = blk * CH3, e1 = min(e0 + CH3, n_edges);
    for (int e = e0 + tid; e < e1; e += 512) {
        const float x = r[3*e], y = r[3*e+1], z = r[3*e+2];
        const float bl = sqrtf(x*x + y*y + z*z);
        int idx = (int)(bl * inv_h); idx = idx > kmax ? kmax : idx;
        const float s = bl - (float)idx * h;
        const float4 q0 = pack8[2*idx];
        const float4 q1 = pack8[2*idx + 1];
        const float drho  = q0.z + s*(2.0f*q1.x + 3.0f*q1.z*s);
        const float rphi  = q0.y + s*(q0.w + s*(q1.y + s*q1.w));
        const float drphi = q0.w + s*(2.0f*q1.y + 3.0f*q1.w*s);
        const float inv_bl = 1.0f / bl;
        const float dphi = (drphi - rphi * inv_bl) * inv_bl;
        const int si = src[e], di = dst[e];
        const float g = Fp[di] * drho + 0.5f * dphi;
        const float coef = g * inv_bl;
        const float fx = coef * x, fy = coef * y, fz = coef * z;
        {
            const int pp = si >> SHIFT_P;
            const int slot = atomicAdd(&cur[pp], 1);
            if (slot < CAP)
                slabF[pp * CAP + slot] = make_int2(
                    (int)(((unsigned)(si & (NPP-1)) << 16) | f2bf(fx)),
                    (int)((f2bf(fy) << 16) | f2bf(fz)));
            else {
                atomicAdd(&ovF[3*si+0], fq(fx));
                atomicAdd(&ovF[3*si+1], fq(fy));
                atomicAdd(&ovF[3*si+2], fq(fz));
            }
        }
        {
            const int pp = di >> SHIFT_P;
            const int slot = atomicAdd(&cur[pp], 1);
            if (slot < CAP)
                slabF[pp * CAP + slot] = make_int2(
                    (int)(((unsigned)(di & (NPP-1)) << 16) | f2bf(-fx)),
                    (int)((f2bf(-fy) << 16) | f2bf(-fz)));
            else {
                atomicAdd(&ovF[3*di+0], fq(-fx));
                atomicAdd(&ovF[3*di+1], fq(-fy));
                atomicAdd(&ovF[3*di+2], fq(-fz));
            }
        }
    }
    __syncthreads();
    const int wave = tid >> 6, lane = tid & 63;
    for (int p = wave; p < P; p += 8) {
        int c = cur[p]; c = c > CAP ? CAP : c;
        int gb = 0;
        if (lane == 0 && c > 0) gb = atomicAdd(&gCurF[p], c);
        gb = __shfl(gb, 0, 64);
        for (int i = lane; i < c; i += 64) {
            const int gi = gb + i;
            if (gi < capF) recF[(size_t)p * capF + gi] = slabF[p * CAP + i];
        }
    }
}

// Accumulate one slice of one partition's force records.
// u32 fixed-point LDS atomics (ds_add_u32): exact mod-2^32, quantum 2^-10.
__global__ void __launch_bounds__(512) eam_p3b(
    const int2* __restrict__ recF, const int* __restrict__ gCurF,
    int* __restrict__ partF, int capF)
{
    __shared__ unsigned acc[NPP * 3];  // 48 KB
    const int tid = threadIdx.x;
    const int p = blockIdx.x / KB, j = blockIdx.x % KB;
    for (int i = tid; i < NPP * 3; i += 512) acc[i] = 0u;
    __syncthreads();
    int cnt = gCurF[p]; cnt = cnt > capF ? capF : cnt;
    const int per = (((cnt + KB - 1) / KB) + 3) & ~3;
    const int lo = j * per, hi = min(lo + per, cnt);
    const int2* seg = recF + (size_t)p * capF;
    int i = lo + 2 * tid;
    for (; i + 6 * 512 + 1 < hi; i += 8 * 512) {
        const uint4 a = *(const uint4*)(seg + i);
        const uint4 b = *(const uint4*)(seg + i + 2 * 512);
        const uint4 c = *(const uint4*)(seg + i + 4 * 512);
        const uint4 d = *(const uint4*)(seg + i + 6 * 512);
        int li;
        li = (int)(a.x >> 16) * 3;
        atomicAdd(&acc[li+0], fq(bf2f_lo(a.x))); atomicAdd(&acc[li+1], fq(bf2f_hi(a.y))); atomicAdd(&acc[li+2], fq(bf2f_lo(a.y)));
        li = (int)(a.z >> 16) * 3;
        atomicAdd(&acc[li+0], fq(bf2f_lo(a.z))); atomicAdd(&acc[li+1], fq(bf2f_hi(a.w))); atomicAdd(&acc[li+2], fq(bf2f_lo(a.w)));
        li = (int)(b.x >> 16) * 3;
        atomicAdd(&acc[li+0], fq(bf2f_lo(b.x))); atomicAdd(&acc[li+1], fq(bf2f_hi(b.y))); atomicAdd(&acc[li+2], fq(bf2f_lo(b.y)));
        li = (int)(b.z >> 16) * 3;
        atomicAdd(&acc[li+0], fq(bf2f_lo(b.z))); atomicAdd(&acc[li+1], fq(bf2f_hi(b.w))); atomicAdd(&acc[li+2], fq(bf2f_lo(b.w)));
        li = (int)(c.x >> 16) * 3;
        atomicAdd(&acc[li+0], fq(bf2f_lo(c.x))); atomicAdd(&acc[li+1], fq(bf2f_hi(c.y))); atomicAdd(&acc[li+2], fq(bf2f_lo(c.y)));
        li = (int)(c.z >> 16) * 3;
        atomicAdd(&acc[li+0], fq(bf2f_lo(c.z))); atomicAdd(&acc[li+1], fq(bf2f_hi(c.w))); atomicAdd(&acc[li+2], fq(bf2f_lo(c.w)));
        li = (int)(d.x >> 16) * 3;
        atomicAdd(&acc[li+0], fq(bf2f_lo(d.x))); atomicAdd(&acc[li+1], fq(bf2f_hi(d.y))); atomicAdd(&acc[li+2], fq(bf2f_lo(d.y)));
        li = (int)(d.z >> 16) * 3;
        atomicAdd(&acc[li+0], fq(bf2f_lo(d.z))); atomicAdd(&acc[li+1], fq(bf2f_hi(d.w))); atomicAdd(&acc[li+2], fq(bf2f_lo(d.w)));
    }
    for (; i + 1 < hi; i += 2 * 512) {
        const uint4 a = *(const uint4*)(seg + i);
        int li = (int)(a.x >> 16) * 3;
        atomicAdd(&acc[li+0], fq(bf2f_lo(a.x))); atomicAdd(&acc[li+1], fq(bf2f_hi(a.y))); atomicAdd(&acc[li+2], fq(bf2f_lo(a.y)));
        li = (int)(a.z >> 16) * 3;
        atomicAdd(&acc[li+0], fq(bf2f_lo(a.z))); atomicAdd(&acc[li+1], fq(bf2f_hi(a.w))); atomicAdd(&acc[li+2], fq(bf2f_lo(a.w)));
    }
    for (int t = (hi & ~1) + tid; t < hi; t += 512) {
        const int2 rc = seg[t];
        const unsigned w0 = (unsigned)rc.x, w1 = (unsigned)rc.y;
        const int li = (int)(w0 >> 16) * 3;
        atomicAdd(&acc[li+0], fq(bf2f_lo(w0)));
        atomicAdd(&acc[li+1], fq(bf2f_hi(w1)));
        atomicAdd(&acc[li+2], fq(bf2f_lo(w1)));
    }
    __syncthreads();
    int* out = partF + (size_t)blockIdx.x * (NPP * 3);
    for (int k = tid; k < NPP * 3; k += 512) out[k] = (int)acc[k];
}

// Merge force partials (exact int sums + overflow) -> outF (dequantized).
__global__ void __launch_bounds__(1024) eam_p3c(
    const int* __restrict__ partF, const unsigned* __restrict__ ovF,
    float* __restrict__ outF, int n_nodes)
{
    const int g = blockIdx.x * 1024 + threadIdx.x;
    if (g >= 3 * n_nodes) return;
    const int n = g / 3, c = g - 3 * n;
    const int p = n >> SHIFT_P, l = n & (NPP - 1);
    int v = (int)ovF[g];
    #pragma unroll
    for (int j = 0; j < KB; ++j)
        v += partF[(size_t)(p * KB + j) * (NPP * 3) + l * 3 + c];
    outF[g] = (float)v * FSTEP;
}

// Fold partial sums -> E (d_out[0]).
__global__ void __launch_bounds__(256) eam_final_e(
    const double* __restrict__ p1, int n1,
    const double* __restrict__ p2, int n2,
    float* __restrict__ outE)
{
    double v = 0.0;
    for (int i = threadIdx.x; i < n1; i += 256) v += p1[i];
    for (int i = threadIdx.x; i < n2; i += 256) v += p2[i];
    const double bs = block_reduce_d(v);
    if (threadIdx.x == 0) *outE = (float)bs;
}

// ===================== fallback (atomic) path =====================

__global__ void __launch_bounds__(256) eam_pass1(
    const float* __restrict__ r, const int* __restrict__ dst,
    const float* __restrict__ rs,
    const float* __restrict__ rad_a, const float* __restrict__ rad_b,
    const float* __restrict__ rad_c, const float* __restrict__ rad_d,
    float* __restrict__ node_rho, double* __restrict__ p1,
    int n_edges, float inv_h, int kmax)
{
    const int e = blockIdx.x * 256 + threadIdx.x;
    double phi_half = 0.0;
    if (e < n_edges) {
        const float x = r[3*e], y = r[3*e+1], z = r[3*e+2];
        const float bl = sqrtf(x*x + y*y + z*z);
        const int idx = clamp_idx((int)(bl * inv_h), kmax);
        const float s = bl - rs[idx];
        const float a0 = rad_a[2*idx], a1 = rad_a[2*idx+1];
        const float b0 = rad_b[2*idx], b1 = rad_b[2*idx+1];
        const float c0 = rad_c[2*idx], c1 = rad_c[2*idx+1];
        const float d0 = rad_d[2*idx], d1 = rad_d[2*idx+1];
        const float rho  = a0 + s*(b0 + s*(c0 + s*d0));
        const float rphi = a1 + s*(b1 + s*(c1 + s*d1));
        unsafeAtomicAdd(&node_rho[dst[e]], rho);
        phi_half = 0.5 * (double)(rphi / bl);
    }
    const double bs = block_reduce_d(phi_half);
    if (threadIdx.x == 0) p1[blockIdx.x] = bs;
}

__global__ void __launch_bounds__(256) eam_pass2(
    const float* __restrict__ node_rho, const float* __restrict__ rhos,
    const float* __restrict__ ea, const float* __restrict__ eb,
    const float* __restrict__ ec, const float* __restrict__ ed,
    float* __restrict__ Fp, double* __restrict__ p2,
    int n_nodes, float inv_h, int kmax)
{
    const int n = blockIdx.x * 256 + threadIdx.x;
    double fsum = 0.0;
    if (n < n_nodes) {
        const float rho = node_rho[n];
        const int idx = clamp_idx((int)(rho * inv_h), kmax);
        const float s = rho - rhos[idx];
        const float A = ea[idx], B = eb[idx], C = ec[idx], D = ed[idx];
        fsum = (double)(A + s*(B + s*(C + s*D)));
        Fp[n] = B + s*(2.0f*C + 3.0f*D*s);
    }
    const double bs = block_reduce_d(fsum);
    if (threadIdx.x == 0) p2[blockIdx.x] = bs;
}

__global__ void __launch_bounds__(256) eam_pass3(
    const float* __restrict__ r, const int* __restrict__ src,
    const int* __restrict__ dst, const float* __restrict__ rs,
    const float* __restrict__ rad_a, const float* __restrict__ rad_b,
    const float* __restrict__ rad_c, const float* __restrict__ rad_d,
    const float* __restrict__ Fp, float* __restrict__ forces,
    int n_edges, float inv_h, int kmax)
{
    const int e = blockIdx.x * 256 + threadIdx.x;
    if (e >= n_edges) return;
    const float x = r[3*e], y = r[3*e+1], z = r[3*e+2];
    const float bl = sqrtf(x*x + y*y + z*z);
    const int idx = clamp_idx((int)(bl * inv_h), kmax);
    const float s = bl - rs[idx];
    const float a1 = rad_a[2*idx+1];
    const float b0 = rad_b[2*idx], b1 = rad_b[2*idx+1];
    const float c0 = rad_c[2*idx], c1 = rad_c[2*idx+1];
    const float d0 = rad_d[2*idx], d1 = rad_d[2*idx+1];
    const float drho  = b0 + s*(2.0f*c0 + 3.0f*d0*s);
    const float rphi  = a1 + s*(b1 + s*(c1 + s*d1));
    const float drphi = b1 + s*(2.0f*c1 + 3.0f*d1*s);
    const float inv_bl = 1.0f / bl;
    const float dphi = (drphi - rphi*inv_bl) * inv_bl;
    const int si = src[e], di = dst[e];
    const float g = Fp[di]*drho + 0.5f*dphi;
    const float coef = g * inv_bl;
    const float fx = coef*x, fy = coef*y, fz = coef*z;
    unsafeAtomicAdd(&forces[3*si+0], fx);
    unsafeAtomicAdd(&forces[3*si+1], fy);
    unsafeAtomicAdd(&forces[3*si+2], fz);
    unsafeAtomicAdd(&forces[3*di+0], -fx);
    unsafeAtomicAdd(&forces[3*di+1], -fy);
    unsafeAtomicAdd(&forces[3*di+2], -fz);
}

// ===================== launcher =====================

extern "C" void kernel_launch(void* const* d_in, const int* in_sizes, int n_in,
                              void* d_out, int out_size, void* d_ws, size_t ws_size,
                              hipStream_t stream) {
    const float* r     = (const float*)d_in[0];
    const int*   src   = (const int*)d_in[1];
    const int*   dst   = (const int*)d_in[2];
    const float* rs    = (const float*)d_in[4];
    const float* rhos  = (const float*)d_in[5];
    const float* rad_a = (const float*)d_in[6];
    const float* rad_b = (const float*)d_in[7];
    const float* rad_c = (const float*)d_in[8];
    const float* rad_d = (const float*)d_in[9];
    const float* ea    = (const float*)d_in[10];
    const float* eb    = (const float*)d_in[11];
    const float* ec    = (const float*)d_in[12];
    const float* ed    = (const float*)d_in[13];

    const int n_edges = in_sizes[0] / 3;
    const int n_nodes = (out_size - 1) / 3;
    const int nr      = in_sizes[4];
    const int nrho    = in_sizes[5];

    float* outE = (float*)d_out;
    float* outF = (float*)d_out + 1;

    const float inv_hr   = (float)((double)(nr - 1) / 6.0);
    const float hr       = (float)(6.0 / (double)(nr - 1));
    const float inv_hrho = (float)((double)(nrho - 1) / 60.0);
    const float hrho     = (float)(60.0 / (double)(nrho - 1));

    auto al = [](size_t x) { return (x + 255) & ~(size_t)255; };
    char* ws = (char*)d_ws;

    const int P    = (n_nodes + NPP - 1) >> SHIFT_P;
    const int nb1a = (n_edges + CH1 - 1) / CH1;
    const int nb3a = (n_edges + CH3 - 1) / CH3;
    const int nb1c = (n_nodes + 1023) / 1024;
    const int nb3c = (3 * n_nodes + 1023) / 1024;
    const int capR = (n_edges / P + n_edges / (8 * P) + 2048) & ~3;
    const int capF = (2 * n_edges / P + n_edges / (4 * P) + 4096) & ~3;

    size_t off = 0;
    float4*   pack8 = (float4*)(ws + off);   off += al((size_t)(nr - 1) * 32);
    float4*   pack4 = (float4*)(ws + off);   off += al((size_t)(nrho - 1) * 16);
    int*      gCur  = (int*)(ws + off);      off += al((size_t)2 * PMAX * 4);
    unsigned* ovR   = (unsigned*)(ws + off); off += al((size_t)n_nodes * 4);
    unsigned* ovF   = (unsigned*)(ws + off); off += al((size_t)n_nodes * 12);
    float*    Fp    = (float*)(ws + off);    off += al((size_t)n_nodes * 4);
    double*   p1b   = (double*)(ws + off);   off += al((size_t)nb1a * 8);
    double*   p2b   = (double*)(ws + off);   off += al((size_t)nb1c * 8);
    float*    partR = (float*)(ws + off);    off += al((size_t)P * KR * NPP * 4);
    int*      partF = (int*)(ws + off);      off += al((size_t)P * KB * NPP * 12);
    unsigned* recR  = (unsigned*)(ws + off); off += al((size_t)P * capR * 4);
    int2*     recF  = (int2*)(ws + off);     off += al((size_t)P * capF * 8);
    const size_t need = off;

    if (P <= PMAX && ws_size >= need) {
        // ---- slab partition path ----
        int* gCurR = gCur;
        int* gCurF = gCur + PMAX;
        hipMemsetAsync(gCur, 0, (size_t)2 * PMAX * 4, stream);
        hipMemsetAsync(ovR, 0, (size_t)n_nodes * 4, stream);
        hipMemsetAsync(ovF, 0, (size_t)n_nodes * 12, stream);
        const int npk = (nr - 1) > (nrho - 1) ? (nr - 1) : (nrho - 1);
        eam_prep<<<(npk + 255) / 256, 256, 0, stream>>>(
            rad_a, rad_b, rad_c, rad_d, ea, eb, ec, ed, pack8, pack4, nr - 1, nrho - 1);
        eam_p1a<<<nb1a, 512, (size_t)P * CAP * 4, stream>>>(
            r, dst, pack8, recR, gCurR, ovR, p1b, n_edges, inv_hr, hr, nr - 2, P, capR);
        eam_p1b<<<P * KR, 512, 0, stream>>>(recR, gCurR, partR, capR);
        eam_p1c<<<nb1c, 1024, 0, stream>>>(
            partR, ovR, pack4, Fp, p2b, n_nodes, inv_hrho, hrho, nrho - 2);
        eam_p3a<<<nb3a, 512, (size_t)P * CAP * 8, stream>>>(
            r, src, dst, pack8, Fp, recF, gCurF, ovF, n_edges, inv_hr, hr, nr - 2, P, capF);
        eam_p3b<<<P * KB, 512, 0, stream>>>(recF, gCurF, partF, capF);
        eam_p3c<<<nb3c, 1024, 0, stream>>>(partF, ovF, outF, n_nodes);
        eam_final_e<<<1, 256, 0, stream>>>(p1b, nb1a, p2b, nb1c, outE);
    } else {
        // ---- fallback atomic path (R1) ----
        size_t o = 0;
        float* node_rho = (float*)(ws + o); o += al((size_t)n_nodes * 4);
        float* Fp2      = (float*)(ws + o); o += al((size_t)n_nodes * 4);
        const int nb_e = (n_edges + 255) / 256;
        const int nb_n = (n_nodes + 255) / 256;
        double* p1 = (double*)(ws + o); o += al((size_t)nb_e * 8);
        double* p2 = (double*)(ws + o);
        hipMemsetAsync(d_out, 0, (size_t)out_size * sizeof(float), stream);
        hipMemsetAsync(node_rho, 0, (size_t)n_nodes * sizeof(float), stream);
        eam_pass1<<<nb_e, 256, 0, stream>>>(r, dst, rs, rad_a, rad_b, rad_c, rad_d,
                                            node_rho, p1, n_edges, inv_hr, nr - 2);
        eam_pass2<<<nb_n, 256, 0, stream>>>(node_rho, rhos, ea, eb, ec, ed,
                                            Fp2, p2, n_nodes, inv_hrho, nrho - 2);
        eam_final_e<<<1, 256, 0, stream>>>(p1, nb_e, p2, nb_n, outE);
        eam_pass3<<<nb_e, 256, 0, stream>>>(r, src, dst, rs, rad_a, rad_b, rad_c, rad_d,
                                            Fp2, outF, n_edges, inv_hr, nr - 2);
    }
}

// Round 10
// 252.575 us; speedup vs baseline: 2.5096x; 2.5096x over previous
//
#include <hip/hip_runtime.h>
#include <math.h>

// EAM potential: E = sum_n F(rho_n) + 0.5 * sum_e phi(bl_e)
//   rho_n = sum_{e: dst[e]=n} density(bl_e)
//   forces = segsum(dEdr, src) - segsum(dEdr, dst)
//
// R10: revert to R8's proven chunked histogram+scan+compact partitioners
// (R9's slab rewrite serialized 5x: per-record atomic->branch->dependent
// store with no batched work). Single trim vs R8: KR 16->8, KB 24->16
// halves partial-array write+read traffic; same atomic patterns.

static constexpr int BLOCK_A = 512;   // partitioner block
static constexpr int EPB     = 4096;  // edges per partitioner block
static constexpr int SHIFT_P = 12;    // log2(nodes per partition)
static constexpr int NPP     = 4096;  // nodes per partition
static constexpr int PMAX    = 32;    // max partitions (LDS arrays)
static constexpr int KR      = 8;     // accumulation slices per partition (rho)
static constexpr int KB      = 16;    // accumulation slices per partition (force)

static constexpr float QSCALE   = 524288.0f;       // 2^19 (rho in [0,2))
static constexpr float QSTEP    = 1.0f / QSCALE;
static constexpr float FSCALE   = 1024.0f;         // 2^10 force quantum
static constexpr float FSTEP    = 1.0f / FSCALE;

__device__ __forceinline__ double block_reduce_d(double v) {
    #pragma unroll
    for (int off = 32; off > 0; off >>= 1)
        v += __shfl_down(v, off, 64);
    __shared__ double smem[16];
    const int lane = threadIdx.x & 63;
    const int wave = threadIdx.x >> 6;
    if (threadIdx.x < 16) smem[threadIdx.x] = 0.0;
    __syncthreads();
    if (lane == 0) smem[wave] = v;
    __syncthreads();
    if (wave == 0) {
        v = (lane < 16) ? smem[lane] : 0.0;
        #pragma unroll
        for (int off = 8; off > 0; off >>= 1)
            v += __shfl_down(v, off, 64);
    }
    return v;  // valid in threadIdx.x == 0
}

__device__ __forceinline__ int clamp_idx(int i, int hi) {
    return i < 0 ? 0 : (i > hi ? hi : i);
}

__device__ __forceinline__ unsigned f2bf(float f) {
    unsigned u = __float_as_uint(f);
    return (u + 0x7FFFu + ((u >> 16) & 1u)) >> 16;   // RNE bf16
}
__device__ __forceinline__ float bf2f_hi(unsigned w) { return __uint_as_float(w & 0xFFFF0000u); }
__device__ __forceinline__ float bf2f_lo(unsigned w) { return __uint_as_float(w << 16); }
// float -> signed fixed-point quanta as unsigned (exact mod-2^32 adds)
__device__ __forceinline__ unsigned fq(float f) {
    float s = f * FSCALE;
    s = fminf(fmaxf(s, -1.0e9f), 1.0e9f);
    return (unsigned)(int)rintf(s);
}

// Interleave spline coeff tables.
__global__ void eam_prep(
    const float* __restrict__ rad_a, const float* __restrict__ rad_b,
    const float* __restrict__ rad_c, const float* __restrict__ rad_d,
    const float* __restrict__ ea, const float* __restrict__ eb,
    const float* __restrict__ ec, const float* __restrict__ ed,
    float4* __restrict__ pack8, float4* __restrict__ pack4,
    int nr1, int nrho1)
{
    const int i = blockIdx.x * 256 + threadIdx.x;
    if (i < nr1) {
        pack8[2*i]   = make_float4(rad_a[2*i], rad_a[2*i+1], rad_b[2*i], rad_b[2*i+1]);
        pack8[2*i+1] = make_float4(rad_c[2*i], rad_c[2*i+1], rad_d[2*i], rad_d[2*i+1]);
    }
    if (i < nrho1)
        pack4[i] = make_float4(ea[i], eb[i], ec[i], ed[i]);
}

// ---- rho chain ----

// Partition rho records (4B: local12<<20 | q20) into P streams; phi partials.
__global__ void __launch_bounds__(BLOCK_A) eam_p1a(
    const float* __restrict__ r, const int* __restrict__ dst,
    const float4* __restrict__ pack8,
    unsigned* __restrict__ recR, int* __restrict__ gCurR, double* __restrict__ p1,
    int n_edges, float inv_h, float h, int kmax, int P, int capR)
{
    constexpr int CH = 4 * BLOCK_A;  // 2048 edges per chunk
    __shared__ int hist[PMAX], base[PMAX], cur[PMAX], gbase[PMAX];
    __shared__ int tot;
    __shared__ unsigned buf[CH];
    __shared__ unsigned char pbk[CH];
    const int tid = threadIdx.x;
    const int e0 = blockIdx.x * EPB;
    const int e1 = min(e0 + EPB, n_edges);
    double phi = 0.0;
    for (int c0 = e0; c0 < e1; c0 += CH) {
        int node[4]; float rho[4]; bool val[4];
        if (tid < P) hist[tid] = 0;
        __syncthreads();
        #pragma unroll
        for (int k = 0; k < 4; ++k) {
            const int e = c0 + k * BLOCK_A + tid;
            val[k] = e < e1;
            node[k] = 0; rho[k] = 0.0f;
            if (val[k]) {
                const float x = r[3*e], y = r[3*e+1], z = r[3*e+2];
                const float bl = sqrtf(x*x + y*y + z*z);
                int idx = (int)(bl * inv_h); idx = idx > kmax ? kmax : idx;
                const float s = bl - (float)idx * h;
                const float4 q0 = pack8[2*idx];
                const float4 q1 = pack8[2*idx + 1];
                rho[k] = q0.x + s*(q0.z + s*(q1.x + s*q1.z));
                const float rphi = q0.y + s*(q0.w + s*(q1.y + s*q1.w));
                phi += 0.5 * (double)(rphi / bl);
                node[k] = dst[e];
                atomicAdd(&hist[node[k] >> SHIFT_P], 1);
            }
        }
        __syncthreads();
        if (tid == 0) {
            int s = 0;
            for (int i = 0; i < P; ++i) { base[i] = s; s += hist[i]; }
            tot = s;
        }
        __syncthreads();
        if (tid < P) {
            cur[tid] = base[tid];
            gbase[tid] = hist[tid] ? atomicAdd(&gCurR[tid], hist[tid]) : 0;
        }
        __syncthreads();
        #pragma unroll
        for (int k = 0; k < 4; ++k) {
            if (val[k]) {
                const int pp = node[k] >> SHIFT_P;
                int q = (int)(rho[k] * QSCALE + 0.5f);
                q = q < 0 ? 0 : (q > 0xFFFFF ? 0xFFFFF : q);
                const int pos = atomicAdd(&cur[pp], 1);
                buf[pos] = ((unsigned)(node[k] & (NPP - 1)) << 20) | (unsigned)q;
                pbk[pos] = (unsigned char)pp;
            }
        }
        __syncthreads();
        const int T = tot;
        for (int i = tid; i < T; i += BLOCK_A) {
            const int pp = pbk[i];
            const int gi = gbase[pp] + (i - base[pp]);
            if (gi < capR) recR[(size_t)pp * capR + gi] = buf[i];
        }
        __syncthreads();
    }
    const double bs = block_reduce_d(phi);
    if (tid == 0) p1[blockIdx.x] = bs;
}

// Accumulate one slice of one partition's rho records (u32 LDS atomics).
__global__ void __launch_bounds__(512) eam_p1b(
    const unsigned* __restrict__ recR, const int* __restrict__ gCurR,
    float* __restrict__ partR, int capR)
{
    __shared__ unsigned acc[NPP];  // 16 KB
    const int tid = threadIdx.x;
    const int p = blockIdx.x / KR, j = blockIdx.x % KR;
    for (int i = tid; i < NPP; i += 512) acc[i] = 0u;
    __syncthreads();
    int cnt = gCurR[p]; cnt = cnt > capR ? capR : cnt;
    const int per = (((cnt + KR - 1) / KR) + 3) & ~3;
    const int lo = j * per, hi = min(lo + per, cnt);
    const unsigned* seg = recR + (size_t)p * capR;
    int i = lo + 4 * tid;
    for (; i + 4 * 512 + 3 < hi; i += 2 * 4 * 512) {
        const uint4 a = *(const uint4*)(seg + i);
        const uint4 b = *(const uint4*)(seg + i + 4 * 512);
        atomicAdd(&acc[a.x >> 20], a.x & 0xFFFFFu);
        atomicAdd(&acc[a.y >> 20], a.y & 0xFFFFFu);
        atomicAdd(&acc[a.z >> 20], a.z & 0xFFFFFu);
        atomicAdd(&acc[a.w >> 20], a.w & 0xFFFFFu);
        atomicAdd(&acc[b.x >> 20], b.x & 0xFFFFFu);
        atomicAdd(&acc[b.y >> 20], b.y & 0xFFFFFu);
        atomicAdd(&acc[b.z >> 20], b.z & 0xFFFFFu);
        atomicAdd(&acc[b.w >> 20], b.w & 0xFFFFFu);
    }
    for (; i + 3 < hi; i += 4 * 512) {
        const uint4 a = *(const uint4*)(seg + i);
        atomicAdd(&acc[a.x >> 20], a.x & 0xFFFFFu);
        atomicAdd(&acc[a.y >> 20], a.y & 0xFFFFFu);
        atomicAdd(&acc[a.z >> 20], a.z & 0xFFFFFu);
        atomicAdd(&acc[a.w >> 20], a.w & 0xFFFFFu);
    }
    for (int t = (hi & ~3) + tid; t < hi; t += 512) {
        const unsigned w = seg[t];
        atomicAdd(&acc[w >> 20], w & 0xFFFFFu);
    }
    __syncthreads();
    float* out = partR + (size_t)blockIdx.x * NPP;
    for (int k = tid; k < NPP; k += 512) out[k] = (float)acc[k] * QSTEP;
}

// Merge rho partials; embedding spline -> Fp, F partial sums.
__global__ void __launch_bounds__(1024) eam_p1c(
    const float* __restrict__ partR, const float4* __restrict__ pack4,
    float* __restrict__ Fp, double* __restrict__ p2,
    int n_nodes, float inv_h, float h, int kmax)
{
    const int n = blockIdx.x * 1024 + threadIdx.x;
    double fsum = 0.0;
    if (n < n_nodes) {
        const int p = n >> SHIFT_P, l = n & (NPP - 1);
        float rho = 0.0f;
        #pragma unroll
        for (int j = 0; j < KR; ++j)
            rho += partR[(size_t)(p * KR + j) * NPP + l];
        int idx = clamp_idx((int)(rho * inv_h), kmax);
        const float s = rho - (float)idx * h;
        const float4 q = pack4[idx];
        fsum = (double)(q.x + s*(q.y + s*(q.z + s*q.w)));
        Fp[n] = q.y + s*(2.0f*q.z + 3.0f*q.w*s);
    }
    const double bs = block_reduce_d(fsum);
    if (threadIdx.x == 0) p2[blockIdx.x] = bs;
}

// ---- force chain ----

// Partition force records (8B: local12<<16|bf16fx, bf16fy<<16|bf16fz).
__global__ void __launch_bounds__(BLOCK_A) eam_p3a(
    const float* __restrict__ r, const int* __restrict__ src, const int* __restrict__ dst,
    const float4* __restrict__ pack8, const float* __restrict__ Fp,
    int2* __restrict__ recF, int* __restrict__ gCurF,
    int n_edges, float inv_h, float h, int kmax, int P, int capF)
{
    constexpr int CH = 2 * BLOCK_A;  // 1024 edges -> 2048 records per chunk
    __shared__ int hist[PMAX], base[PMAX], cur[PMAX], gbase[PMAX];
    __shared__ int tot;
    __shared__ int2 buf[2 * CH];
    __shared__ unsigned char pbk[2 * CH];
    const int tid = threadIdx.x;
    const int e0 = blockIdx.x * EPB;
    const int e1 = min(e0 + EPB, n_edges);
    for (int c0 = e0; c0 < e1; c0 += CH) {
        int si[2], di[2]; float fx[2], fy[2], fz[2]; bool val[2];
        if (tid < P) hist[tid] = 0;
        __syncthreads();
        #pragma unroll
        for (int k = 0; k < 2; ++k) {
            const int e = c0 + k * BLOCK_A + tid;
            val[k] = e < e1;
            si[k] = 0; di[k] = 0; fx[k] = fy[k] = fz[k] = 0.0f;
            if (val[k]) {
                const float x = r[3*e], y = r[3*e+1], z = r[3*e+2];
                const float bl = sqrtf(x*x + y*y + z*z);
                int idx = (int)(bl * inv_h); idx = idx > kmax ? kmax : idx;
                const float s = bl - (float)idx * h;
                const float4 q0 = pack8[2*idx];
                const float4 q1 = pack8[2*idx + 1];
                const float drho  = q0.z + s*(2.0f*q1.x + 3.0f*q1.z*s);
                const float rphi  = q0.y + s*(q0.w + s*(q1.y + s*q1.w));
                const float drphi = q0.w + s*(2.0f*q1.y + 3.0f*q1.w*s);
                const float inv_bl = 1.0f / bl;
                const float dphi = (drphi - rphi * inv_bl) * inv_bl;
                si[k] = src[e]; di[k] = dst[e];
                const float g = Fp[di[k]] * drho + 0.5f * dphi;
                const float coef = g * inv_bl;
                fx[k] = coef * x; fy[k] = coef * y; fz[k] = coef * z;
                atomicAdd(&hist[si[k] >> SHIFT_P], 1);
                atomicAdd(&hist[di[k] >> SHIFT_P], 1);
            }
        }
        __syncthreads();
        if (tid == 0) {
            int s = 0;
            for (int i = 0; i < P; ++i) { base[i] = s; s += hist[i]; }
            tot = s;
        }
        __syncthreads();
        if (tid < P) {
            cur[tid] = base[tid];
            gbase[tid] = hist[tid] ? atomicAdd(&gCurF[tid], hist[tid]) : 0;
        }
        __syncthreads();
        #pragma unroll
        for (int k = 0; k < 2; ++k) {
            if (val[k]) {
                {
                    const int pp = si[k] >> SHIFT_P;
                    const int pos = atomicAdd(&cur[pp], 1);
                    buf[pos] = make_int2(
                        (int)(((unsigned)(si[k] & (NPP-1)) << 16) | f2bf(fx[k])),
                        (int)((f2bf(fy[k]) << 16) | f2bf(fz[k])));
                    pbk[pos] = (unsigned char)pp;
                }
                {
                    const int pp = di[k] >> SHIFT_P;
                    const int pos = atomicAdd(&cur[pp], 1);
                    buf[pos] = make_int2(
                        (int)(((unsigned)(di[k] & (NPP-1)) << 16) | f2bf(-fx[k])),
                        (int)((f2bf(-fy[k]) << 16) | f2bf(-fz[k])));
                    pbk[pos] = (unsigned char)pp;
                }
            }
        }
        __syncthreads();
        const int T = tot;
        for (int i = tid; i < T; i += BLOCK_A) {
            const int pp = pbk[i];
            const int gi = gbase[pp] + (i - base[pp]);
            if (gi < capF) recF[(size_t)pp * capF + gi] = buf[i];
        }
        __syncthreads();
    }
}

// Accumulate one slice of one partition's force records.
// u32 fixed-point LDS atomics (ds_add_u32): exact mod-2^32, quantum 2^-10.
__global__ void __launch_bounds__(512) eam_p3b(
    const int2* __restrict__ recF, const int* __restrict__ gCurF,
    int* __restrict__ partF, int capF)
{
    __shared__ unsigned acc[NPP * 3];  // 48 KB
    const int tid = threadIdx.x;
    const int p = blockIdx.x / KB, j = blockIdx.x % KB;
    for (int i = tid; i < NPP * 3; i += 512) acc[i] = 0u;
    __syncthreads();
    int cnt = gCurF[p]; cnt = cnt > capF ? capF : cnt;
    const int per = (((cnt + KB - 1) / KB) + 3) & ~3;
    const int lo = j * per, hi = min(lo + per, cnt);
    const int2* seg = recF + (size_t)p * capF;
    int i = lo + 2 * tid;
    for (; i + 6 * 512 + 1 < hi; i += 8 * 512) {
        const uint4 a = *(const uint4*)(seg + i);
        const uint4 b = *(const uint4*)(seg + i + 2 * 512);
        const uint4 c = *(const uint4*)(seg + i + 4 * 512);
        const uint4 d = *(const uint4*)(seg + i + 6 * 512);
        int li;
        li = (int)(a.x >> 16) * 3;
        atomicAdd(&acc[li+0], fq(bf2f_lo(a.x))); atomicAdd(&acc[li+1], fq(bf2f_hi(a.y))); atomicAdd(&acc[li+2], fq(bf2f_lo(a.y)));
        li = (int)(a.z >> 16) * 3;
        atomicAdd(&acc[li+0], fq(bf2f_lo(a.z))); atomicAdd(&acc[li+1], fq(bf2f_hi(a.w))); atomicAdd(&acc[li+2], fq(bf2f_lo(a.w)));
        li = (int)(b.x >> 16) * 3;
        atomicAdd(&acc[li+0], fq(bf2f_lo(b.x))); atomicAdd(&acc[li+1], fq(bf2f_hi(b.y))); atomicAdd(&acc[li+2], fq(bf2f_lo(b.y)));
        li = (int)(b.z >> 16) * 3;
        atomicAdd(&acc[li+0], fq(bf2f_lo(b.z))); atomicAdd(&acc[li+1], fq(bf2f_hi(b.w))); atomicAdd(&acc[li+2], fq(bf2f_lo(b.w)));
        li = (int)(c.x >> 16) * 3;
        atomicAdd(&acc[li+0], fq(bf2f_lo(c.x))); atomicAdd(&acc[li+1], fq(bf2f_hi(c.y))); atomicAdd(&acc[li+2], fq(bf2f_lo(c.y)));
        li = (int)(c.z >> 16) * 3;
        atomicAdd(&acc[li+0], fq(bf2f_lo(c.z))); atomicAdd(&acc[li+1], fq(bf2f_hi(c.w))); atomicAdd(&acc[li+2], fq(bf2f_lo(c.w)));
        li = (int)(d.x >> 16) * 3;
        atomicAdd(&acc[li+0], fq(bf2f_lo(d.x))); atomicAdd(&acc[li+1], fq(bf2f_hi(d.y))); atomicAdd(&acc[li+2], fq(bf2f_lo(d.y)));
        li = (int)(d.z >> 16) * 3;
        atomicAdd(&acc[li+0], fq(bf2f_lo(d.z))); atomicAdd(&acc[li+1], fq(bf2f_hi(d.w))); atomicAdd(&acc[li+2], fq(bf2f_lo(d.w)));
    }
    for (; i + 1 < hi; i += 2 * 512) {
        const uint4 a = *(const uint4*)(seg + i);
        int li = (int)(a.x >> 16) * 3;
        atomicAdd(&acc[li+0], fq(bf2f_lo(a.x))); atomicAdd(&acc[li+1], fq(bf2f_hi(a.y))); atomicAdd(&acc[li+2], fq(bf2f_lo(a.y)));
        li = (int)(a.z >> 16) * 3;
        atomicAdd(&acc[li+0], fq(bf2f_lo(a.z))); atomicAdd(&acc[li+1], fq(bf2f_hi(a.w))); atomicAdd(&acc[li+2], fq(bf2f_lo(a.w)));
    }
    for (int t = (hi & ~1) + tid; t < hi; t += 512) {
        const int2 rc = seg[t];
        const unsigned w0 = (unsigned)rc.x, w1 = (unsigned)rc.y;
        const int li = (int)(w0 >> 16) * 3;
        atomicAdd(&acc[li+0], fq(bf2f_lo(w0)));
        atomicAdd(&acc[li+1], fq(bf2f_hi(w1)));
        atomicAdd(&acc[li+2], fq(bf2f_lo(w1)));
    }
    __syncthreads();
    int* out = partF + (size_t)blockIdx.x * (NPP * 3);
    for (int k = tid; k < NPP * 3; k += 512) out[k] = (int)acc[k];
}

// Merge force partials (exact int sums) -> outF (coalesced, dequantized).
__global__ void __launch_bounds__(1024) eam_p3c(
    const int* __restrict__ partF, float* __restrict__ outF, int n_nodes)
{
    const int g = blockIdx.x * 1024 + threadIdx.x;
    if (g >= 3 * n_nodes) return;
    const int n = g / 3, c = g - 3 * n;
    const int p = n >> SHIFT_P, l = n & (NPP - 1);
    int v = 0;
    #pragma unroll
    for (int j = 0; j < KB; ++j)
        v += partF[(size_t)(p * KB + j) * (NPP * 3) + l * 3 + c];
    outF[g] = (float)v * FSTEP;
}

// Fold partial sums -> E (d_out[0]).
__global__ void __launch_bounds__(256) eam_final_e(
    const double* __restrict__ p1, int n1,
    const double* __restrict__ p2, int n2,
    float* __restrict__ outE)
{
    double v = 0.0;
    for (int i = threadIdx.x; i < n1; i += 256) v += p1[i];
    for (int i = threadIdx.x; i < n2; i += 256) v += p2[i];
    const double bs = block_reduce_d(v);
    if (threadIdx.x == 0) *outE = (float)bs;
}

// ===================== fallback (atomic) path =====================

__global__ void __launch_bounds__(256) eam_pass1(
    const float* __restrict__ r, const int* __restrict__ dst,
    const float* __restrict__ rs,
    const float* __restrict__ rad_a, const float* __restrict__ rad_b,
    const float* __restrict__ rad_c, const float* __restrict__ rad_d,
    float* __restrict__ node_rho, double* __restrict__ p1,
    int n_edges, float inv_h, int kmax)
{
    const int e = blockIdx.x * 256 + threadIdx.x;
    double phi_half = 0.0;
    if (e < n_edges) {
        const float x = r[3*e], y = r[3*e+1], z = r[3*e+2];
        const float bl = sqrtf(x*x + y*y + z*z);
        const int idx = clamp_idx((int)(bl * inv_h), kmax);
        const float s = bl - rs[idx];
        const float a0 = rad_a[2*idx], a1 = rad_a[2*idx+1];
        const float b0 = rad_b[2*idx], b1 = rad_b[2*idx+1];
        const float c0 = rad_c[2*idx], c1 = rad_c[2*idx+1];
        const float d0 = rad_d[2*idx], d1 = rad_d[2*idx+1];
        const float rho  = a0 + s*(b0 + s*(c0 + s*d0));
        const float rphi = a1 + s*(b1 + s*(c1 + s*d1));
        unsafeAtomicAdd(&node_rho[dst[e]], rho);
        phi_half = 0.5 * (double)(rphi / bl);
    }
    const double bs = block_reduce_d(phi_half);
    if (threadIdx.x == 0) p1[blockIdx.x] = bs;
}

__global__ void __launch_bounds__(256) eam_pass2(
    const float* __restrict__ node_rho, const float* __restrict__ rhos,
    const float* __restrict__ ea, const float* __restrict__ eb,
    const float* __restrict__ ec, const float* __restrict__ ed,
    float* __restrict__ Fp, double* __restrict__ p2,
    int n_nodes, float inv_h, int kmax)
{
    const int n = blockIdx.x * 256 + threadIdx.x;
    double fsum = 0.0;
    if (n < n_nodes) {
        const float rho = node_rho[n];
        const int idx = clamp_idx((int)(rho * inv_h), kmax);
        const float s = rho - rhos[idx];
        const float A = ea[idx], B = eb[idx], C = ec[idx], D = ed[idx];
        fsum = (double)(A + s*(B + s*(C + s*D)));
        Fp[n] = B + s*(2.0f*C + 3.0f*D*s);
    }
    const double bs = block_reduce_d(fsum);
    if (threadIdx.x == 0) p2[blockIdx.x] = bs;
}

__global__ void __launch_bounds__(256) eam_pass3(
    const float* __restrict__ r, const int* __restrict__ src,
    const int* __restrict__ dst, const float* __restrict__ rs,
    const float* __restrict__ rad_a, const float* __restrict__ rad_b,
    const float* __restrict__ rad_c, const float* __restrict__ rad_d,
    const float* __restrict__ Fp, float* __restrict__ forces,
    int n_edges, float inv_h, int kmax)
{
    const int e = blockIdx.x * 256 + threadIdx.x;
    if (e >= n_edges) return;
    const float x = r[3*e], y = r[3*e+1], z = r[3*e+2];
    const float bl = sqrtf(x*x + y*y + z*z);
    const int idx = clamp_idx((int)(bl * inv_h), kmax);
    const float s = bl - rs[idx];
    const float a1 = rad_a[2*idx+1];
    const float b0 = rad_b[2*idx], b1 = rad_b[2*idx+1];
    const float c0 = rad_c[2*idx], c1 = rad_c[2*idx+1];
    const float d0 = rad_d[2*idx], d1 = rad_d[2*idx+1];
    const float drho  = b0 + s*(2.0f*c0 + 3.0f*d0*s);
    const float rphi  = a1 + s*(b1 + s*(c1 + s*d1));
    const float drphi = b1 + s*(2.0f*c1 + 3.0f*d1*s);
    const float inv_bl = 1.0f / bl;
    const float dphi = (drphi - rphi*inv_bl) * inv_bl;
    const int si = src[e], di = dst[e];
    const float g = Fp[di]*drho + 0.5f*dphi;
    const float coef = g * inv_bl;
    const float fx = coef*x, fy = coef*y, fz = coef*z;
    unsafeAtomicAdd(&forces[3*si+0], fx);
    unsafeAtomicAdd(&forces[3*si+1], fy);
    unsafeAtomicAdd(&forces[3*si+2], fz);
    unsafeAtomicAdd(&forces[3*di+0], -fx);
    unsafeAtomicAdd(&forces[3*di+1], -fy);
    unsafeAtomicAdd(&forces[3*di+2], -fz);
}

// ===================== launcher =====================

extern "C" void kernel_launch(void* const* d_in, const int* in_sizes, int n_in,
                              void* d_out, int out_size, void* d_ws, size_t ws_size,
                              hipStream_t stream) {
    const float* r     = (const float*)d_in[0];
    const int*   src   = (const int*)d_in[1];
    const int*   dst   = (const int*)d_in[2];
    const float* rs    = (const float*)d_in[4];
    const float* rhos  = (const float*)d_in[5];
    const float* rad_a = (const float*)d_in[6];
    const float* rad_b = (const float*)d_in[7];
    const float* rad_c = (const float*)d_in[8];
    const float* rad_d = (const float*)d_in[9];
    const float* ea    = (const float*)d_in[10];
    const float* eb    = (const float*)d_in[11];
    const float* ec    = (const float*)d_in[12];
    const float* ed    = (const float*)d_in[13];

    const int n_edges = in_sizes[0] / 3;
    const int n_nodes = (out_size - 1) / 3;
    const int nr      = in_sizes[4];
    const int nrho    = in_sizes[5];

    float* outE = (float*)d_out;
    float* outF = (float*)d_out + 1;

    const float inv_hr   = (float)((double)(nr - 1) / 6.0);
    const float hr       = (float)(6.0 / (double)(nr - 1));
    const float inv_hrho = (float)((double)(nrho - 1) / 60.0);
    const float hrho     = (float)(60.0 / (double)(nrho - 1));

    auto al = [](size_t x) { return (x + 255) & ~(size_t)255; };
    char* ws = (char*)d_ws;

    const int P    = (n_nodes + NPP - 1) >> SHIFT_P;
    const int nbA  = (n_edges + EPB - 1) / EPB;
    const int nb1c = (n_nodes + 1023) / 1024;
    const int nb3c = (3 * n_nodes + 1023) / 1024;
    const int capR = (n_edges / P + n_edges / (8 * P) + 2048) & ~3;
    const int capF = (2 * n_edges / P + n_edges / (4 * P) + 4096) & ~3;

    size_t off = 0;
    float4*   pack8 = (float4*)(ws + off);   off += al((size_t)(nr - 1) * 32);
    float4*   pack4 = (float4*)(ws + off);   off += al((size_t)(nrho - 1) * 16);
    int*      gCur  = (int*)(ws + off);      off += al((size_t)2 * PMAX * 4);
    float*    Fp    = (float*)(ws + off);    off += al((size_t)n_nodes * 4);
    double*   p1b   = (double*)(ws + off);   off += al((size_t)nbA * 8);
    double*   p2b   = (double*)(ws + off);   off += al((size_t)nb1c * 8);
    float*    partR = (float*)(ws + off);    off += al((size_t)P * KR * NPP * 4);
    int*      partF = (int*)(ws + off);      off += al((size_t)P * KB * NPP * 12);
    unsigned* recR  = (unsigned*)(ws + off); off += al((size_t)P * capR * 4);
    int2*     recF  = (int2*)(ws + off);     off += al((size_t)P * capF * 8);
    const size_t need = off;

    if (P <= PMAX && ws_size >= need) {
        // ---- partition path ----
        int* gCurR = gCur;
        int* gCurF = gCur + PMAX;
        hipMemsetAsync(gCur, 0, (size_t)2 * PMAX * 4, stream);
        const int npk = (nr - 1) > (nrho - 1) ? (nr - 1) : (nrho - 1);
        eam_prep<<<(npk + 255) / 256, 256, 0, stream>>>(
            rad_a, rad_b, rad_c, rad_d, ea, eb, ec, ed, pack8, pack4, nr - 1, nrho - 1);
        eam_p1a<<<nbA, BLOCK_A, 0, stream>>>(
            r, dst, pack8, recR, gCurR, p1b, n_edges, inv_hr, hr, nr - 2, P, capR);
        eam_p1b<<<P * KR, 512, 0, stream>>>(recR, gCurR, partR, capR);
        eam_p1c<<<nb1c, 1024, 0, stream>>>(
            partR, pack4, Fp, p2b, n_nodes, inv_hrho, hrho, nrho - 2);
        eam_p3a<<<nbA, BLOCK_A, 0, stream>>>(
            r, src, dst, pack8, Fp, recF, gCurF, n_edges, inv_hr, hr, nr - 2, P, capF);
        eam_p3b<<<P * KB, 512, 0, stream>>>(recF, gCurF, partF, capF);
        eam_p3c<<<nb3c, 1024, 0, stream>>>(partF, outF, n_nodes);
        eam_final_e<<<1, 256, 0, stream>>>(p1b, nbA, p2b, nb1c, outE);
    } else {
        // ---- fallback atomic path (R1) ----
        size_t o = 0;
        float* node_rho = (float*)(ws + o); o += al((size_t)n_nodes * 4);
        float* Fp2      = (float*)(ws + o); o += al((size_t)n_nodes * 4);
        const int nb_e = (n_edges + 255) / 256;
        const int nb_n = (n_nodes + 255) / 256;
        double* p1 = (double*)(ws + o); o += al((size_t)nb_e * 8);
        double* p2 = (double*)(ws + o);
        hipMemsetAsync(d_out, 0, (size_t)out_size * sizeof(float), stream);
        hipMemsetAsync(node_rho, 0, (size_t)n_nodes * sizeof(float), stream);
        eam_pass1<<<nb_e, 256, 0, stream>>>(r, dst, rs, rad_a, rad_b, rad_c, rad_d,
                                            node_rho, p1, n_edges, inv_hr, nr - 2);
        eam_pass2<<<nb_n, 256, 0, stream>>>(node_rho, rhos, ea, eb, ec, ed,
                                            Fp2, p2, n_nodes, inv_hrho, nrho - 2);
        eam_final_e<<<1, 256, 0, stream>>>(p1, nb_e, p2, nb_n, outE);
        eam_pass3<<<nb_e, 256, 0, stream>>>(r, src, dst, rs, rad_a, rad_b, rad_c, rad_d,
                                            Fp2, outF, n_edges, inv_hr, nr - 2);
    }
}

// Round 11
// 236.413 us; speedup vs baseline: 2.6812x; 1.0684x over previous
//
#include <hip/hip_runtime.h>
#include <math.h>

// EAM potential: E = sum_n F(rho_n) + 0.5 * sum_e phi(bl_e)
//   rho_n = sum_{e: dst[e]=n} density(bl_e)
//   forces = segsum(dEdr, src) - segsum(dEdr, dst)
//
// R11 (on R8/R10 structure): one chunk per partitioner block (fewer scans,
// 4 barriers/block), wave-0 shuffle scan instead of serial thread-0 scan,
// bf16 negation via sign-bit XOR, gCur zeroing folded into eam_prep.
// Algorithm, layouts, atomic patterns otherwise identical to R10.

static constexpr int SHIFT_P = 12;    // log2(nodes per partition)
static constexpr int NPP     = 4096;  // nodes per partition
static constexpr int PMAX    = 32;    // max partitions (LDS arrays)
static constexpr int KR      = 8;     // accumulation slices per partition (rho)
static constexpr int KB      = 16;    // accumulation slices per partition (force)
static constexpr int CH1     = 4096;  // edges per p1a block (1 chunk, 8/thread)
static constexpr int CH3     = 2048;  // edges per p3a block (1 chunk, 4/thread)

static constexpr float QSCALE = 524288.0f;   // 2^19 (rho in [0,2))
static constexpr float QSTEP  = 1.0f / QSCALE;
static constexpr float FSCALE = 1024.0f;     // 2^10 force quantum
static constexpr float FSTEP  = 1.0f / FSCALE;

__device__ __forceinline__ double block_reduce_d(double v) {
    #pragma unroll
    for (int off = 32; off > 0; off >>= 1)
        v += __shfl_down(v, off, 64);
    __shared__ double smem[16];
    const int lane = threadIdx.x & 63;
    const int wave = threadIdx.x >> 6;
    if (threadIdx.x < 16) smem[threadIdx.x] = 0.0;
    __syncthreads();
    if (lane == 0) smem[wave] = v;
    __syncthreads();
    if (wave == 0) {
        v = (lane < 16) ? smem[lane] : 0.0;
        #pragma unroll
        for (int off = 8; off > 0; off >>= 1)
            v += __shfl_down(v, off, 64);
    }
    return v;  // valid in threadIdx.x == 0
}

__device__ __forceinline__ int clamp_idx(int i, int hi) {
    return i < 0 ? 0 : (i > hi ? hi : i);
}

__device__ __forceinline__ unsigned f2bf(float f) {
    unsigned u = __float_as_uint(f);
    return (u + 0x7FFFu + ((u >> 16) & 1u)) >> 16;   // RNE bf16
}
__device__ __forceinline__ float bf2f_hi(unsigned w) { return __uint_as_float(w & 0xFFFF0000u); }
__device__ __forceinline__ float bf2f_lo(unsigned w) { return __uint_as_float(w << 16); }
// float -> signed fixed-point quanta as unsigned (exact mod-2^32 adds)
__device__ __forceinline__ unsigned fq(float f) {
    float s = f * FSCALE;
    s = fminf(fmaxf(s, -1.0e9f), 1.0e9f);
    return (unsigned)(int)rintf(s);
}

// Interleave spline coeff tables; zero the global cursors.
__global__ void eam_prep(
    const float* __restrict__ rad_a, const float* __restrict__ rad_b,
    const float* __restrict__ rad_c, const float* __restrict__ rad_d,
    const float* __restrict__ ea, const float* __restrict__ eb,
    const float* __restrict__ ec, const float* __restrict__ ed,
    float4* __restrict__ pack8, float4* __restrict__ pack4,
    int* __restrict__ gCur, int nr1, int nrho1)
{
    const int i = blockIdx.x * 256 + threadIdx.x;
    if (blockIdx.x == 0 && threadIdx.x < 2 * PMAX) gCur[threadIdx.x] = 0;
    if (i < nr1) {
        pack8[2*i]   = make_float4(rad_a[2*i], rad_a[2*i+1], rad_b[2*i], rad_b[2*i+1]);
        pack8[2*i+1] = make_float4(rad_c[2*i], rad_c[2*i+1], rad_d[2*i], rad_d[2*i+1]);
    }
    if (i < nrho1)
        pack4[i] = make_float4(ea[i], eb[i], ec[i], ed[i]);
}

// ---- rho chain ----

// Partition rho records (4B: local12<<20 | q20); one 4096-edge chunk per block.
__global__ void __launch_bounds__(512) eam_p1a(
    const float* __restrict__ r, const int* __restrict__ dst,
    const float4* __restrict__ pack8,
    unsigned* __restrict__ recR, int* __restrict__ gCurR, double* __restrict__ p1,
    int n_edges, float inv_h, float h, int kmax, int P, int capR)
{
    __shared__ int hist[PMAX], base[PMAX], cur[PMAX], gbase[PMAX];
    __shared__ int tot;
    __shared__ unsigned buf[CH1];
    __shared__ unsigned char pbk[CH1];
    const int tid = threadIdx.x;
    const int e0 = blockIdx.x * CH1;
    const int e1 = min(e0 + CH1, n_edges);
    double phi = 0.0;
    unsigned rec[8]; int pk[8]; bool val[8];
    if (tid < P) hist[tid] = 0;
    __syncthreads();
    #pragma unroll
    for (int k = 0; k < 8; ++k) {
        const int e = e0 + k * 512 + tid;
        val[k] = e < e1;
        rec[k] = 0; pk[k] = 0;
        if (val[k]) {
            const float x = r[3*e], y = r[3*e+1], z = r[3*e+2];
            const float bl = sqrtf(x*x + y*y + z*z);
            int idx = (int)(bl * inv_h); idx = idx > kmax ? kmax : idx;
            const float s = bl - (float)idx * h;
            const float4 q0 = pack8[2*idx];
            const float4 q1 = pack8[2*idx + 1];
            const float rho  = q0.x + s*(q0.z + s*(q1.x + s*q1.z));
            const float rphi = q0.y + s*(q0.w + s*(q1.y + s*q1.w));
            phi += 0.5 * (double)(rphi / bl);
            const int node = dst[e];
            pk[k] = node >> SHIFT_P;
            int q = (int)(rho * QSCALE + 0.5f);
            q = q < 0 ? 0 : (q > 0xFFFFF ? 0xFFFFF : q);
            rec[k] = ((unsigned)(node & (NPP - 1)) << 20) | (unsigned)q;
            atomicAdd(&hist[pk[k]], 1);
        }
    }
    __syncthreads();
    if (tid < 64) {                       // wave-0 shuffle scan
        const int lane = tid;
        const int hv = (lane < P) ? hist[lane] : 0;
        int s = hv;
        #pragma unroll
        for (int off = 1; off < 32; off <<= 1) {
            const int t = __shfl_up(s, off, 64);
            if (lane >= off) s += t;
        }
        if (lane < P) {
            base[lane] = s - hv;
            cur[lane]  = s - hv;
            gbase[lane] = hv ? atomicAdd(&gCurR[lane], hv) : 0;
        }
        if (lane == P - 1) tot = s;
    }
    __syncthreads();
    #pragma unroll
    for (int k = 0; k < 8; ++k) {
        if (val[k]) {
            const int pos = atomicAdd(&cur[pk[k]], 1);
            buf[pos] = rec[k];
            pbk[pos] = (unsigned char)pk[k];
        }
    }
    __syncthreads();
    const int T = tot;
    for (int i = tid; i < T; i += 512) {
        const int pp = pbk[i];
        const int gi = gbase[pp] + (i - base[pp]);
        if (gi < capR) recR[(size_t)pp * capR + gi] = buf[i];
    }
    const double bs = block_reduce_d(phi);
    if (tid == 0) p1[blockIdx.x] = bs;
}

// Accumulate one slice of one partition's rho records (u32 LDS atomics).
__global__ void __launch_bounds__(512) eam_p1b(
    const unsigned* __restrict__ recR, const int* __restrict__ gCurR,
    float* __restrict__ partR, int capR)
{
    __shared__ unsigned acc[NPP];  // 16 KB
    const int tid = threadIdx.x;
    const int p = blockIdx.x / KR, j = blockIdx.x % KR;
    for (int i = tid; i < NPP; i += 512) acc[i] = 0u;
    __syncthreads();
    int cnt = gCurR[p]; cnt = cnt > capR ? capR : cnt;
    const int per = (((cnt + KR - 1) / KR) + 3) & ~3;
    const int lo = j * per, hi = min(lo + per, cnt);
    const unsigned* seg = recR + (size_t)p * capR;
    int i = lo + 4 * tid;
    for (; i + 4 * 512 + 3 < hi; i += 2 * 4 * 512) {
        const uint4 a = *(const uint4*)(seg + i);
        const uint4 b = *(const uint4*)(seg + i + 4 * 512);
        atomicAdd(&acc[a.x >> 20], a.x & 0xFFFFFu);
        atomicAdd(&acc[a.y >> 20], a.y & 0xFFFFFu);
        atomicAdd(&acc[a.z >> 20], a.z & 0xFFFFFu);
        atomicAdd(&acc[a.w >> 20], a.w & 0xFFFFFu);
        atomicAdd(&acc[b.x >> 20], b.x & 0xFFFFFu);
        atomicAdd(&acc[b.y >> 20], b.y & 0xFFFFFu);
        atomicAdd(&acc[b.z >> 20], b.z & 0xFFFFFu);
        atomicAdd(&acc[b.w >> 20], b.w & 0xFFFFFu);
    }
    for (; i + 3 < hi; i += 4 * 512) {
        const uint4 a = *(const uint4*)(seg + i);
        atomicAdd(&acc[a.x >> 20], a.x & 0xFFFFFu);
        atomicAdd(&acc[a.y >> 20], a.y & 0xFFFFFu);
        atomicAdd(&acc[a.z >> 20], a.z & 0xFFFFFu);
        atomicAdd(&acc[a.w >> 20], a.w & 0xFFFFFu);
    }
    for (int t = (hi & ~3) + tid; t < hi; t += 512) {
        const unsigned w = seg[t];
        atomicAdd(&acc[w >> 20], w & 0xFFFFFu);
    }
    __syncthreads();
    float* out = partR + (size_t)blockIdx.x * NPP;
    for (int k = tid; k < NPP; k += 512) out[k] = (float)acc[k] * QSTEP;
}

// Merge rho partials; embedding spline -> Fp, F partial sums.
__global__ void __launch_bounds__(1024) eam_p1c(
    const float* __restrict__ partR, const float4* __restrict__ pack4,
    float* __restrict__ Fp, double* __restrict__ p2,
    int n_nodes, float inv_h, float h, int kmax)
{
    const int n = blockIdx.x * 1024 + threadIdx.x;
    double fsum = 0.0;
    if (n < n_nodes) {
        const int p = n >> SHIFT_P, l = n & (NPP - 1);
        float rho = 0.0f;
        #pragma unroll
        for (int j = 0; j < KR; ++j)
            rho += partR[(size_t)(p * KR + j) * NPP + l];
        int idx = clamp_idx((int)(rho * inv_h), kmax);
        const float s = rho - (float)idx * h;
        const float4 q = pack4[idx];
        fsum = (double)(q.x + s*(q.y + s*(q.z + s*q.w)));
        Fp[n] = q.y + s*(2.0f*q.z + 3.0f*q.w*s);
    }
    const double bs = block_reduce_d(fsum);
    if (threadIdx.x == 0) p2[blockIdx.x] = bs;
}

// ---- force chain ----

// Partition force records (8B); one 2048-edge chunk (4096 records) per block.
__global__ void __launch_bounds__(512) eam_p3a(
    const float* __restrict__ r, const int* __restrict__ src, const int* __restrict__ dst,
    const float4* __restrict__ pack8, const float* __restrict__ Fp,
    int2* __restrict__ recF, int* __restrict__ gCurF,
    int n_edges, float inv_h, float h, int kmax, int P, int capF)
{
    __shared__ int hist[PMAX], base[PMAX], cur[PMAX], gbase[PMAX];
    __shared__ int tot;
    __shared__ int2 buf[2 * CH3];
    __shared__ unsigned char pbk[2 * CH3];
    const int tid = threadIdx.x;
    const int e0 = blockIdx.x * CH3;
    const int e1 = min(e0 + CH3, n_edges);
    int2 sa[4], da[4]; int ps[4], pd[4]; bool val[4];
    if (tid < P) hist[tid] = 0;
    __syncthreads();
    #pragma unroll
    for (int k = 0; k < 4; ++k) {
        const int e = e0 + k * 512 + tid;
        val[k] = e < e1;
        ps[k] = pd[k] = 0;
        sa[k] = da[k] = make_int2(0, 0);
        if (val[k]) {
            const float x = r[3*e], y = r[3*e+1], z = r[3*e+2];
            const float bl = sqrtf(x*x + y*y + z*z);
            int idx = (int)(bl * inv_h); idx = idx > kmax ? kmax : idx;
            const float s = bl - (float)idx * h;
            const float4 q0 = pack8[2*idx];
            const float4 q1 = pack8[2*idx + 1];
            const float drho  = q0.z + s*(2.0f*q1.x + 3.0f*q1.z*s);
            const float rphi  = q0.y + s*(q0.w + s*(q1.y + s*q1.w));
            const float drphi = q0.w + s*(2.0f*q1.y + 3.0f*q1.w*s);
            const float inv_bl = 1.0f / bl;
            const float dphi = (drphi - rphi * inv_bl) * inv_bl;
            const int si = src[e], di = dst[e];
            const float g = Fp[di] * drho + 0.5f * dphi;
            const float coef = g * inv_bl;
            const unsigned bx = f2bf(coef * x), by = f2bf(coef * y), bz = f2bf(coef * z);
            ps[k] = si >> SHIFT_P;
            pd[k] = di >> SHIFT_P;
            sa[k] = make_int2((int)(((unsigned)(si & (NPP-1)) << 16) | bx),
                              (int)((by << 16) | bz));
            // negation = bf16 sign-bit flip (RNE is symmetric)
            da[k] = make_int2((int)(((unsigned)(di & (NPP-1)) << 16) | (bx ^ 0x8000u)),
                              (int)(((by ^ 0x8000u) << 16) | (bz ^ 0x8000u)));
            atomicAdd(&hist[ps[k]], 1);
            atomicAdd(&hist[pd[k]], 1);
        }
    }
    __syncthreads();
    if (tid < 64) {                       // wave-0 shuffle scan
        const int lane = tid;
        const int hv = (lane < P) ? hist[lane] : 0;
        int s = hv;
        #pragma unroll
        for (int off = 1; off < 32; off <<= 1) {
            const int t = __shfl_up(s, off, 64);
            if (lane >= off) s += t;
        }
        if (lane < P) {
            base[lane] = s - hv;
            cur[lane]  = s - hv;
            gbase[lane] = hv ? atomicAdd(&gCurF[lane], hv) : 0;
        }
        if (lane == P - 1) tot = s;
    }
    __syncthreads();
    #pragma unroll
    for (int k = 0; k < 4; ++k) {
        if (val[k]) {
            int pos = atomicAdd(&cur[ps[k]], 1);
            buf[pos] = sa[k];
            pbk[pos] = (unsigned char)ps[k];
            pos = atomicAdd(&cur[pd[k]], 1);
            buf[pos] = da[k];
            pbk[pos] = (unsigned char)pd[k];
        }
    }
    __syncthreads();
    const int T = tot;
    for (int i = tid; i < T; i += 512) {
        const int pp = pbk[i];
        const int gi = gbase[pp] + (i - base[pp]);
        if (gi < capF) recF[(size_t)pp * capF + gi] = buf[i];
    }
}

// Accumulate one slice of one partition's force records.
// u32 fixed-point LDS atomics (ds_add_u32): exact mod-2^32, quantum 2^-10.
__global__ void __launch_bounds__(512) eam_p3b(
    const int2* __restrict__ recF, const int* __restrict__ gCurF,
    int* __restrict__ partF, int capF)
{
    __shared__ unsigned acc[NPP * 3];  // 48 KB
    const int tid = threadIdx.x;
    const int p = blockIdx.x / KB, j = blockIdx.x % KB;
    for (int i = tid; i < NPP * 3; i += 512) acc[i] = 0u;
    __syncthreads();
    int cnt = gCurF[p]; cnt = cnt > capF ? capF : cnt;
    const int per = (((cnt + KB - 1) / KB) + 3) & ~3;
    const int lo = j * per, hi = min(lo + per, cnt);
    const int2* seg = recF + (size_t)p * capF;
    int i = lo + 2 * tid;
    for (; i + 6 * 512 + 1 < hi; i += 8 * 512) {
        const uint4 a = *(const uint4*)(seg + i);
        const uint4 b = *(const uint4*)(seg + i + 2 * 512);
        const uint4 c = *(const uint4*)(seg + i + 4 * 512);
        const uint4 d = *(const uint4*)(seg + i + 6 * 512);
        int li;
        li = (int)(a.x >> 16) * 3;
        atomicAdd(&acc[li+0], fq(bf2f_lo(a.x))); atomicAdd(&acc[li+1], fq(bf2f_hi(a.y))); atomicAdd(&acc[li+2], fq(bf2f_lo(a.y)));
        li = (int)(a.z >> 16) * 3;
        atomicAdd(&acc[li+0], fq(bf2f_lo(a.z))); atomicAdd(&acc[li+1], fq(bf2f_hi(a.w))); atomicAdd(&acc[li+2], fq(bf2f_lo(a.w)));
        li = (int)(b.x >> 16) * 3;
        atomicAdd(&acc[li+0], fq(bf2f_lo(b.x))); atomicAdd(&acc[li+1], fq(bf2f_hi(b.y))); atomicAdd(&acc[li+2], fq(bf2f_lo(b.y)));
        li = (int)(b.z >> 16) * 3;
        atomicAdd(&acc[li+0], fq(bf2f_lo(b.z))); atomicAdd(&acc[li+1], fq(bf2f_hi(b.w))); atomicAdd(&acc[li+2], fq(bf2f_lo(b.w)));
        li = (int)(c.x >> 16) * 3;
        atomicAdd(&acc[li+0], fq(bf2f_lo(c.x))); atomicAdd(&acc[li+1], fq(bf2f_hi(c.y))); atomicAdd(&acc[li+2], fq(bf2f_lo(c.y)));
        li = (int)(c.z >> 16) * 3;
        atomicAdd(&acc[li+0], fq(bf2f_lo(c.z))); atomicAdd(&acc[li+1], fq(bf2f_hi(c.w))); atomicAdd(&acc[li+2], fq(bf2f_lo(c.w)));
        li = (int)(d.x >> 16) * 3;
        atomicAdd(&acc[li+0], fq(bf2f_lo(d.x))); atomicAdd(&acc[li+1], fq(bf2f_hi(d.y))); atomicAdd(&acc[li+2], fq(bf2f_lo(d.y)));
        li = (int)(d.z >> 16) * 3;
        atomicAdd(&acc[li+0], fq(bf2f_lo(d.z))); atomicAdd(&acc[li+1], fq(bf2f_hi(d.w))); atomicAdd(&acc[li+2], fq(bf2f_lo(d.w)));
    }
    for (; i + 1 < hi; i += 2 * 512) {
        const uint4 a = *(const uint4*)(seg + i);
        int li = (int)(a.x >> 16) * 3;
        atomicAdd(&acc[li+0], fq(bf2f_lo(a.x))); atomicAdd(&acc[li+1], fq(bf2f_hi(a.y))); atomicAdd(&acc[li+2], fq(bf2f_lo(a.y)));
        li = (int)(a.z >> 16) * 3;
        atomicAdd(&acc[li+0], fq(bf2f_lo(a.z))); atomicAdd(&acc[li+1], fq(bf2f_hi(a.w))); atomicAdd(&acc[li+2], fq(bf2f_lo(a.w)));
    }
    for (int t = (hi & ~1) + tid; t < hi; t += 512) {
        const int2 rc = seg[t];
        const unsigned w0 = (unsigned)rc.x, w1 = (unsigned)rc.y;
        const int li = (int)(w0 >> 16) * 3;
        atomicAdd(&acc[li+0], fq(bf2f_lo(w0)));
        atomicAdd(&acc[li+1], fq(bf2f_hi(w1)));
        atomicAdd(&acc[li+2], fq(bf2f_lo(w1)));
    }
    __syncthreads();
    int* out = partF + (size_t)blockIdx.x * (NPP * 3);
    for (int k = tid; k < NPP * 3; k += 512) out[k] = (int)acc[k];
}

// Merge force partials (exact int sums) -> outF (coalesced, dequantized).
__global__ void __launch_bounds__(1024) eam_p3c(
    const int* __restrict__ partF, float* __restrict__ outF, int n_nodes)
{
    const int g = blockIdx.x * 1024 + threadIdx.x;
    if (g >= 3 * n_nodes) return;
    const int n = g / 3, c = g - 3 * n;
    const int p = n >> SHIFT_P, l = n & (NPP - 1);
    int v = 0;
    #pragma unroll
    for (int j = 0; j < KB; ++j)
        v += partF[(size_t)(p * KB + j) * (NPP * 3) + l * 3 + c];
    outF[g] = (float)v * FSTEP;
}

// Fold partial sums -> E (d_out[0]).
__global__ void __launch_bounds__(256) eam_final_e(
    const double* __restrict__ p1, int n1,
    const double* __restrict__ p2, int n2,
    float* __restrict__ outE)
{
    double v = 0.0;
    for (int i = threadIdx.x; i < n1; i += 256) v += p1[i];
    for (int i = threadIdx.x; i < n2; i += 256) v += p2[i];
    const double bs = block_reduce_d(v);
    if (threadIdx.x == 0) *outE = (float)bs;
}

// ===================== fallback (atomic) path =====================

__global__ void __launch_bounds__(256) eam_pass1(
    const float* __restrict__ r, const int* __restrict__ dst,
    const float* __restrict__ rs,
    const float* __restrict__ rad_a, const float* __restrict__ rad_b,
    const float* __restrict__ rad_c, const float* __restrict__ rad_d,
    float* __restrict__ node_rho, double* __restrict__ p1,
    int n_edges, float inv_h, int kmax)
{
    const int e = blockIdx.x * 256 + threadIdx.x;
    double phi_half = 0.0;
    if (e < n_edges) {
        const float x = r[3*e], y = r[3*e+1], z = r[3*e+2];
        const float bl = sqrtf(x*x + y*y + z*z);
        const int idx = clamp_idx((int)(bl * inv_h), kmax);
        const float s = bl - rs[idx];
        const float a0 = rad_a[2*idx], a1 = rad_a[2*idx+1];
        const float b0 = rad_b[2*idx], b1 = rad_b[2*idx+1];
        const float c0 = rad_c[2*idx], c1 = rad_c[2*idx+1];
        const float d0 = rad_d[2*idx], d1 = rad_d[2*idx+1];
        const float rho  = a0 + s*(b0 + s*(c0 + s*d0));
        const float rphi = a1 + s*(b1 + s*(c1 + s*d1));
        unsafeAtomicAdd(&node_rho[dst[e]], rho);
        phi_half = 0.5 * (double)(rphi / bl);
    }
    const double bs = block_reduce_d(phi_half);
    if (threadIdx.x == 0) p1[blockIdx.x] = bs;
}

__global__ void __launch_bounds__(256) eam_pass2(
    const float* __restrict__ node_rho, const float* __restrict__ rhos,
    const float* __restrict__ ea, const float* __restrict__ eb,
    const float* __restrict__ ec, const float* __restrict__ ed,
    float* __restrict__ Fp, double* __restrict__ p2,
    int n_nodes, float inv_h, int kmax)
{
    const int n = blockIdx.x * 256 + threadIdx.x;
    double fsum = 0.0;
    if (n < n_nodes) {
        const float rho = node_rho[n];
        const int idx = clamp_idx((int)(rho * inv_h), kmax);
        const float s = rho - rhos[idx];
        const float A = ea[idx], B = eb[idx], C = ec[idx], D = ed[idx];
        fsum = (double)(A + s*(B + s*(C + s*D)));
        Fp[n] = B + s*(2.0f*C + 3.0f*D*s);
    }
    const double bs = block_reduce_d(fsum);
    if (threadIdx.x == 0) p2[blockIdx.x] = bs;
}

__global__ void __launch_bounds__(256) eam_pass3(
    const float* __restrict__ r, const int* __restrict__ src,
    const int* __restrict__ dst, const float* __restrict__ rs,
    const float* __restrict__ rad_a, const float* __restrict__ rad_b,
    const float* __restrict__ rad_c, const float* __restrict__ rad_d,
    const float* __restrict__ Fp, float* __restrict__ forces,
    int n_edges, float inv_h, int kmax)
{
    const int e = blockIdx.x * 256 + threadIdx.x;
    if (e >= n_edges) return;
    const float x = r[3*e], y = r[3*e+1], z = r[3*e+2];
    const float bl = sqrtf(x*x + y*y + z*z);
    const int idx = clamp_idx((int)(bl * inv_h), kmax);
    const float s = bl - rs[idx];
    const float a1 = rad_a[2*idx+1];
    const float b0 = rad_b[2*idx], b1 = rad_b[2*idx+1];
    const float c0 = rad_c[2*idx], c1 = rad_c[2*idx+1];
    const float d0 = rad_d[2*idx], d1 = rad_d[2*idx+1];
    const float drho  = b0 + s*(2.0f*c0 + 3.0f*d0*s);
    const float rphi  = a1 + s*(b1 + s*(c1 + s*d1));
    const float drphi = b1 + s*(2.0f*c1 + 3.0f*d1*s);
    const float inv_bl = 1.0f / bl;
    const float dphi = (drphi - rphi*inv_bl) * inv_bl;
    const int si = src[e], di = dst[e];
    const float g = Fp[di]*drho + 0.5f*dphi;
    const float coef = g * inv_bl;
    const float fx = coef*x, fy = coef*y, fz = coef*z;
    unsafeAtomicAdd(&forces[3*si+0], fx);
    unsafeAtomicAdd(&forces[3*si+1], fy);
    unsafeAtomicAdd(&forces[3*si+2], fz);
    unsafeAtomicAdd(&forces[3*di+0], -fx);
    unsafeAtomicAdd(&forces[3*di+1], -fy);
    unsafeAtomicAdd(&forces[3*di+2], -fz);
}

// ===================== launcher =====================

extern "C" void kernel_launch(void* const* d_in, const int* in_sizes, int n_in,
                              void* d_out, int out_size, void* d_ws, size_t ws_size,
                              hipStream_t stream) {
    const float* r     = (const float*)d_in[0];
    const int*   src   = (const int*)d_in[1];
    const int*   dst   = (const int*)d_in[2];
    const float* rs    = (const float*)d_in[4];
    const float* rhos  = (const float*)d_in[5];
    const float* rad_a = (const float*)d_in[6];
    const float* rad_b = (const float*)d_in[7];
    const float* rad_c = (const float*)d_in[8];
    const float* rad_d = (const float*)d_in[9];
    const float* ea    = (const float*)d_in[10];
    const float* eb    = (const float*)d_in[11];
    const float* ec    = (const float*)d_in[12];
    const float* ed    = (const float*)d_in[13];

    const int n_edges = in_sizes[0] / 3;
    const int n_nodes = (out_size - 1) / 3;
    const int nr      = in_sizes[4];
    const int nrho    = in_sizes[5];

    float* outE = (float*)d_out;
    float* outF = (float*)d_out + 1;

    const float inv_hr   = (float)((double)(nr - 1) / 6.0);
    const float hr       = (float)(6.0 / (double)(nr - 1));
    const float inv_hrho = (float)((double)(nrho - 1) / 60.0);
    const float hrho     = (float)(60.0 / (double)(nrho - 1));

    auto al = [](size_t x) { return (x + 255) & ~(size_t)255; };
    char* ws = (char*)d_ws;

    const int P    = (n_nodes + NPP - 1) >> SHIFT_P;
    const int nb1a = (n_edges + CH1 - 1) / CH1;
    const int nb3a = (n_edges + CH3 - 1) / CH3;
    const int nb1c = (n_nodes + 1023) / 1024;
    const int nb3c = (3 * n_nodes + 1023) / 1024;
    const int capR = (n_edges / P + n_edges / (8 * P) + 2048) & ~3;
    const int capF = (2 * n_edges / P + n_edges / (4 * P) + 4096) & ~3;

    size_t off = 0;
    float4*   pack8 = (float4*)(ws + off);   off += al((size_t)(nr - 1) * 32);
    float4*   pack4 = (float4*)(ws + off);   off += al((size_t)(nrho - 1) * 16);
    int*      gCur  = (int*)(ws + off);      off += al((size_t)2 * PMAX * 4);
    float*    Fp    = (float*)(ws + off);    off += al((size_t)n_nodes * 4);
    double*   p1b   = (double*)(ws + off);   off += al((size_t)nb1a * 8);
    double*   p2b   = (double*)(ws + off);   off += al((size_t)nb1c * 8);
    float*    partR = (float*)(ws + off);    off += al((size_t)P * KR * NPP * 4);
    int*      partF = (int*)(ws + off);      off += al((size_t)P * KB * NPP * 12);
    unsigned* recR  = (unsigned*)(ws + off); off += al((size_t)P * capR * 4);
    int2*     recF  = (int2*)(ws + off);     off += al((size_t)P * capF * 8);
    const size_t need = off;

    if (P <= PMAX && ws_size >= need) {
        // ---- partition path ----
        int* gCurR = gCur;
        int* gCurF = gCur + PMAX;
        const int npk = (nr - 1) > (nrho - 1) ? (nr - 1) : (nrho - 1);
        eam_prep<<<(npk + 255) / 256, 256, 0, stream>>>(
            rad_a, rad_b, rad_c, rad_d, ea, eb, ec, ed, pack8, pack4, gCur, nr - 1, nrho - 1);
        eam_p1a<<<nb1a, 512, 0, stream>>>(
            r, dst, pack8, recR, gCurR, p1b, n_edges, inv_hr, hr, nr - 2, P, capR);
        eam_p1b<<<P * KR, 512, 0, stream>>>(recR, gCurR, partR, capR);
        eam_p1c<<<nb1c, 1024, 0, stream>>>(
            partR, pack4, Fp, p2b, n_nodes, inv_hrho, hrho, nrho - 2);
        eam_p3a<<<nb3a, 512, 0, stream>>>(
            r, src, dst, pack8, Fp, recF, gCurF, n_edges, inv_hr, hr, nr - 2, P, capF);
        eam_p3b<<<P * KB, 512, 0, stream>>>(recF, gCurF, partF, capF);
        eam_p3c<<<nb3c, 1024, 0, stream>>>(partF, outF, n_nodes);
        eam_final_e<<<1, 256, 0, stream>>>(p1b, nb1a, p2b, nb1c, outE);
    } else {
        // ---- fallback atomic path (R1) ----
        size_t o = 0;
        float* node_rho = (float*)(ws + o); o += al((size_t)n_nodes * 4);
        float* Fp2      = (float*)(ws + o); o += al((size_t)n_nodes * 4);
        const int nb_e = (n_edges + 255) / 256;
        const int nb_n = (n_nodes + 255) / 256;
        double* p1 = (double*)(ws + o); o += al((size_t)nb_e * 8);
        double* p2 = (double*)(ws + o);
        hipMemsetAsync(d_out, 0, (size_t)out_size * sizeof(float), stream);
        hipMemsetAsync(node_rho, 0, (size_t)n_nodes * sizeof(float), stream);
        eam_pass1<<<nb_e, 256, 0, stream>>>(r, dst, rs, rad_a, rad_b, rad_c, rad_d,
                                            node_rho, p1, n_edges, inv_hr, nr - 2);
        eam_pass2<<<nb_n, 256, 0, stream>>>(node_rho, rhos, ea, eb, ec, ed,
                                            Fp2, p2, n_nodes, inv_hrho, nrho - 2);
        eam_final_e<<<1, 256, 0, stream>>>(p1, nb_e, p2, nb_n, outE);
        eam_pass3<<<nb_e, 256, 0, stream>>>(r, src, dst, rs, rad_a, rad_b, rad_c, rad_d,
                                            Fp2, outF, n_edges, inv_hr, nr - 2);
    }
}